// Round 6
// baseline (142.668 us; speedup 1.0000x reference)
//
#include <hip/hip_runtime.h>
#include <stdint.h>

using bf16x8 = __attribute__((ext_vector_type(8))) short;
using f32x4  = __attribute__((ext_vector_type(4))) float;

#define DEVINL __device__ __forceinline__

DEVINL unsigned short f2bf(float f) {
  union { float f; unsigned u; } v; v.f = f;
  unsigned u = v.u;
  return (unsigned short)((u + 0x7FFFu + ((u >> 16) & 1u)) >> 16);
}
DEVINL float bf2f(unsigned short h) {
  union { unsigned u; float f; } v; v.u = ((unsigned)h) << 16;
  return v.f;
}

DEVINL void gload_lds16(const void* g, void* l) {
  __builtin_amdgcn_global_load_lds(
      (const __attribute__((address_space(1))) void*)g,
      (__attribute__((address_space(3))) void*)l, 16, 0, 0);
}

// ---------------------------------------------------------------------------
// Core 128x128 bf16 GEMM tile (m97 structure): A (row-major bf16, leading dim
// ld), B (row-major bf16, ld), C = A·B^T (+bias) over Klen. BK=64, 4 waves
// (2x2), per-wave 64x64 via 4x4 frags of mfma_f32_16x16x32_bf16.
// ---------------------------------------------------------------------------
template<int OUT_BF16, int HAS_BIAS>
DEVINL void gemm_core(const unsigned short* __restrict__ A,
                      const unsigned short* __restrict__ B,
                      void* __restrict__ C,
                      const float* __restrict__ bias,
                      int Klen, int ld, int Cld,
                      int arow0, int brow0, int crow0, int ccol0)
{
  __shared__ __align__(16) unsigned short As[128 * 64];
  __shared__ __align__(16) unsigned short Bs[128 * 64];

  const int t    = threadIdx.x;
  const int wave = t >> 6;
  const int lane = t & 63;
  const int wr   = (wave >> 1) << 6;   // 0 or 64
  const int wc   = (wave & 1) << 6;    // 0 or 64
  const int lrow = lane & 15;
  const int kg   = lane >> 4;          // 0..3

  f32x4 acc[4][4];
#pragma unroll
  for (int r = 0; r < 4; ++r)
#pragma unroll
    for (int q = 0; q < 4; ++q) acc[r][q] = (f32x4){0.f, 0.f, 0.f, 0.f};

  // staging: LDS row-major [128][64]; wave-uniform dst + lane*16 (gload_lds rule)
  const int srow = t >> 3;             // 0..31 (pass p adds p*32)
  const int scol = (t & 7) << 3;       // bf16 element offset (16B granules)
  const unsigned short* aSrc = A + (size_t)(arow0 + srow) * ld + scol;
  const unsigned short* bSrc = B + (size_t)(brow0 + srow) * ld + scol;
  char* aDst = (char*)As + wave * 1024;
  char* bDst = (char*)Bs + wave * 1024;

  for (int k0 = 0; k0 < Klen; k0 += 64) {
#pragma unroll
    for (int p = 0; p < 4; ++p) {
      gload_lds16(aSrc + (size_t)(p * 32) * ld + k0, aDst + p * 4096);
      gload_lds16(bSrc + (size_t)(p * 32) * ld + k0, bDst + p * 4096);
    }
    __syncthreads();
#pragma unroll
    for (int kk = 0; kk < 64; kk += 32) {
      bf16x8 af[4], bq[4];
#pragma unroll
      for (int r = 0; r < 4; ++r)
        af[r] = *(const bf16x8*)&As[(wr + r * 16 + lrow) * 64 + kk + kg * 8];
#pragma unroll
      for (int q = 0; q < 4; ++q)
        bq[q] = *(const bf16x8*)&Bs[(wc + q * 16 + lrow) * 64 + kk + kg * 8];
#pragma unroll
      for (int r = 0; r < 4; ++r)
#pragma unroll
        for (int q = 0; q < 4; ++q)
          acc[r][q] = __builtin_amdgcn_mfma_f32_16x16x32_bf16(af[r], bq[q], acc[r][q], 0, 0, 0);
    }
    __syncthreads();
  }

  // epilogue: C/D layout col=lane&15, row=(lane>>4)*4+v  [m89/m91 verified]
#pragma unroll
  for (int r = 0; r < 4; ++r) {
#pragma unroll
    for (int q = 0; q < 4; ++q) {
      const int col = ccol0 + wc + q * 16 + lrow;
      const float bv = HAS_BIAS ? bias[col] : 0.f;
#pragma unroll
      for (int v = 0; v < 4; ++v) {
        const int row = crow0 + wr + r * 16 + (kg << 2) + v;
        const float val = acc[r][q][v] + bv;
        if (OUT_BF16)
          ((unsigned short*)C)[(size_t)row * Cld + col] = f2bf(val);
        else
          ((float*)C)[(size_t)row * Cld + col] = val;
      }
    }
  }
}

// ---------------------------------------------------------------------------
// mega1 (split-K x2): bids 0..639  -> H0h[kh][p] partial = XR[m(p)]·w1cat[j(p)]^T
//                     bids 640..831 -> W2ENh[kh][s] partial = WEN·w2t_s^T
// 832 uniform blocks, each K=1024.
// ---------------------------------------------------------------------------
__global__ __launch_bounds__(256) void mega1_k(const unsigned short* __restrict__ xrb,
                                               const unsigned short* __restrict__ w1cat,
                                               const unsigned short* __restrict__ wen,
                                               const unsigned short* __restrict__ w2t,
                                               unsigned short* __restrict__ H0h,
                                               unsigned short* __restrict__ W2ENh) {
  const int bid = blockIdx.x;
  if (bid < 640) {
    const int p = bid >> 5, rem = bid & 31;
    const int kh = rem & 1, tile = rem >> 1;
    const int rt = tile >> 2, ct = tile & 3;
    const int MM[20] = {0,1,2,3, 0,1,2, 1,2,3, 0,1, 1,2, 2,3, 0,1,2,3};
    const int JJ[20] = {0,0,0,0, 1,1,1, 2,2,2, 3,3, 4,4, 5,5, 6,7,8,9};
    gemm_core<1, 0>(xrb + kh * 1024, w1cat + kh * 1024, H0h + (size_t)kh * 5242880,
                    nullptr, 1024, 2048, 512,
                    MM[p] * 512 + rt * 128, JJ[p] * 512 + ct * 128,
                    p * 512 + rt * 128, ct * 128);
  } else {
    const int b2 = bid - 640;
    const int s = b2 / 48, rem2 = b2 % 48;
    const int kh = rem2 & 1, tile = rem2 >> 1;
    const int rt = tile >> 2, ct = tile & 3;   // rt 0..5, ct 0..3
    gemm_core<1, 0>(wen + kh * 1024, w2t + kh * 1024, W2ENh + (size_t)kh * 1572864,
                    nullptr, 1024, 2048, 512,
                    rt * 128, s * 512 + ct * 128,
                    s * 768 + rt * 128, ct * 128);
  }
}

// gemmF: EN0 = h1(7680x512) @ W2EN_s^T + ENb_s   (fp32 out, 768 cols)
__global__ __launch_bounds__(256) void gemmF_k(const unsigned short* __restrict__ h1,
                                               const unsigned short* __restrict__ W2EN,
                                               const float* __restrict__ ENb,
                                               float* __restrict__ EN0) {
  const int y = blockIdx.y;                  // 0..59 row tiles
  const int c = y >> 2;
  const int s = (c < 4) ? 1 : (c < 10) ? 2 : (c < 14) ? 3 : 4;
  gemm_core<0, 1>(h1, W2EN, EN0, ENb + (size_t)(s - 1) * 768, 512, 512, 768,
                  y * 128, (s - 1) * 768 + blockIdx.x * 128,
                  y * 128, blockIdx.x * 128);
}

// ---------------------------------------------------------------------------
// prep_all: all input casts/layout builds in ONE dispatch (17664 blocks).
//  [0,10240)      prep_w1cat    [10240,14336) prep_xr     [14336,15360) prep_w2t
//  [15360,16896)  prep_wen      [16896,17664) prep_enb
// ---------------------------------------------------------------------------
__global__ __launch_bounds__(256) void prep_all_k(const float* __restrict__ x,
                                                  const float* w11, const float* w12,
                                                  const float* w13, const float* w14,
                                                  const float* w21, const float* w22,
                                                  const float* w23, const float* w24,
                                                  const float* __restrict__ wemb,
                                                  const float* __restrict__ wnode,
                                                  const float* b21, const float* b22,
                                                  const float* b23, const float* b24,
                                                  unsigned short* __restrict__ xrb,
                                                  unsigned short* __restrict__ w1cat,
                                                  unsigned short* __restrict__ w2t,
                                                  unsigned short* __restrict__ wen,
                                                  float* __restrict__ ENb) {
  __shared__ float lds[64][65];
  const int bid = blockIdx.x;
  if (bid < 10240) {                    // ---- w1cat: (5120 x 2048) bf16
    const int tid = bid * 256 + threadIdx.x;
    const int r = tid >> 9;
    const int k = (tid & 511) << 2;
    const int j = r >> 9, o = r & 511;
    const float* src; int s, tt;
    if (j == 0)      { src = w11; s = 1; tt = 0; }
    else if (j < 3)  { src = w12; s = 2; tt = j - 1; }
    else if (j < 6)  { src = w13; s = 3; tt = j - 3; }
    else             { src = w14; s = 4; tt = j - 6; }
    const float4 vv = *(const float4*)(src + (size_t)o * (s * 2048) + tt * 2048 + k);
    ushort4 ov;
    ov.x = f2bf(vv.x); ov.y = f2bf(vv.y); ov.z = f2bf(vv.z); ov.w = f2bf(vv.w);
    *(ushort4*)(w1cat + (size_t)r * 2048 + k) = ov;
  } else if (bid < 14336) {             // ---- xr: relu(x) -> (2048 x 2048) bf16
    const int tid = (bid - 10240) * 256 + threadIdx.x;
    const int r = tid >> 9;
    const int k = (tid & 511) << 2;
    const int m = r >> 9, b = r & 511;
    const float4 vv = *(const float4*)(x + ((size_t)(b * 4 + m)) * 2048 + k);
    ushort4 o;
    o.x = f2bf(fmaxf(vv.x, 0.f)); o.y = f2bf(fmaxf(vv.y, 0.f));
    o.z = f2bf(fmaxf(vv.z, 0.f)); o.w = f2bf(fmaxf(vv.w, 0.f));
    *(ushort4*)(xrb + (size_t)r * 2048 + k) = o;
  } else if (bid < 15360) {             // ---- w2t: transpose w2_s -> (512 x 2048) bf16
    const int idx = bid - 14336;
    const int s = idx >> 8, rem = idx & 255;
    const int rt = rem >> 3, ct = rem & 7;
    const float* src = (s == 0) ? w21 : (s == 1) ? w22 : (s == 2) ? w23 : w24;
    const int tr = threadIdx.x >> 4;            // 0..15
    const int tc = (threadIdx.x & 15) << 2;     // 0..60
#pragma unroll
    for (int i = 0; i < 4; ++i) {
      const float4 v = *(const float4*)(src + (size_t)(rt * 64 + tr + 16 * i) * 512 + ct * 64 + tc);
      lds[tr + 16 * i][tc + 0] = v.x; lds[tr + 16 * i][tc + 1] = v.y;
      lds[tr + 16 * i][tc + 2] = v.z; lds[tr + 16 * i][tc + 3] = v.w;
    }
    __syncthreads();
#pragma unroll
    for (int i = 0; i < 4; ++i) {
      ushort4 ov;
      ov.x = f2bf(lds[tc + 0][tr + 16 * i]); ov.y = f2bf(lds[tc + 1][tr + 16 * i]);
      ov.z = f2bf(lds[tc + 2][tr + 16 * i]); ov.w = f2bf(lds[tc + 3][tr + 16 * i]);
      *(ushort4*)(w2t + ((size_t)s * 512 + ct * 64 + tr + 16 * i) * 2048 + rt * 64 + tc) = ov;
    }
  } else if (bid < 16896) {             // ---- wen: [w_emb; w_node; pad] -> (768 x 2048) bf16
    const int tid = (bid - 15360) * 256 + threadIdx.x;
    const int r = tid >> 9;
    const int k = (tid & 511) << 2;
    float4 vv = make_float4(0.f, 0.f, 0.f, 0.f);
    if (r < 300)       vv = *(const float4*)(wemb + (size_t)r * 2048 + k);
    else if (r < 691)  vv = *(const float4*)(wnode + (size_t)(r - 300) * 2048 + k);
    ushort4 ov;
    ov.x = f2bf(vv.x); ov.y = f2bf(vv.y); ov.z = f2bf(vv.z); ov.w = f2bf(vv.w);
    *(ushort4*)(wen + (size_t)r * 2048 + k) = ov;
  } else {                              // ---- enb: ENb[s][e] = dot(WEN_e, b2_s)
    const int w = (bid - 16896) * 4 + (threadIdx.x >> 6);  // 0..3071
    const int lane = threadIdx.x & 63;
    const int s = w / 768, e = w % 768;
    const float* b2 = (s == 0) ? b21 : (s == 1) ? b22 : (s == 2) ? b23 : b24;
    float acc = 0.f;
    if (e < 691) {
      const float* row = (e < 300) ? (wemb + (size_t)e * 2048) : (wnode + (size_t)(e - 300) * 2048);
#pragma unroll
      for (int i = 0; i < 8; ++i) {
        const float4 a  = *(const float4*)(row + i * 256 + lane * 4);
        const float4 bb = *(const float4*)(b2  + i * 256 + lane * 4);
        acc += a.x * bb.x + a.y * bb.y + a.z * bb.z + a.w * bb.w;
      }
    }
#pragma unroll
    for (int off = 32; off; off >>= 1) acc += __shfl_down(acc, off);
    if (lane == 0) ENb[w] = acc;
  }
}

// ---------------------------------------------------------------------------
// post1: bids [0,7680)  combine1: h1 = relu(b1_s + sum_t (H0h0+H0h1)[P[c][t]])
//        bids [7680,9216) W2EN = W2ENh0 + W2ENh1  (bf16 halves -> bf16)
// ---------------------------------------------------------------------------
__global__ __launch_bounds__(128) void post1_k(const unsigned short* __restrict__ H0h,
                                               unsigned short* __restrict__ h1,
                                               const float* __restrict__ b11,
                                               const float* __restrict__ b12,
                                               const float* __restrict__ b13,
                                               const float* __restrict__ b14,
                                               const unsigned short* __restrict__ W2ENh,
                                               unsigned short* __restrict__ W2EN) {
  const int bid = blockIdx.x;
  if (bid < 7680) {
    const int cb = bid;                  // c*512+b
    const int c = cb >> 9, b = cb & 511;
    const int s = (c < 4) ? 1 : (c < 10) ? 2 : (c < 14) ? 3 : 4;
    const unsigned char P[15][4] = {
      {0,0,0,0},{1,0,0,0},{2,0,0,0},{3,0,0,0},
      {4,7,0,0},{4,8,0,0},{4,9,0,0},{5,8,0,0},{5,9,0,0},{6,9,0,0},
      {10,12,14,0},{10,12,15,0},{10,13,15,0},{11,13,15,0},
      {16,17,18,19}};
    const float* b1 = (s == 1) ? b11 : (s == 2) ? b12 : (s == 3) ? b13 : b14;
    const int o = threadIdx.x << 2;
    float4 a = *(const float4*)(b1 + o);
    for (int t = 0; t < s; ++t) {
      const int p = P[c][t];
      const size_t base = ((size_t)(p * 512 + b)) * 512 + o;
      const ushort4 h0 = *(const ushort4*)(H0h + base);
      const ushort4 h1v = *(const ushort4*)(H0h + 5242880 + base);
      a.x += bf2f(h0.x) + bf2f(h1v.x); a.y += bf2f(h0.y) + bf2f(h1v.y);
      a.z += bf2f(h0.z) + bf2f(h1v.z); a.w += bf2f(h0.w) + bf2f(h1v.w);
    }
    ushort4 ov;
    ov.x = f2bf(fmaxf(a.x, 0.f)); ov.y = f2bf(fmaxf(a.y, 0.f));
    ov.z = f2bf(fmaxf(a.z, 0.f)); ov.w = f2bf(fmaxf(a.w, 0.f));
    *(ushort4*)(h1 + (size_t)cb * 512 + o) = ov;
  } else {
    const int idx = bid - 7680;          // 0..1535, 1024 elems per block
    const size_t off = (size_t)idx * 1024 + (size_t)threadIdx.x * 8;
    const bf16x8 a0 = *(const bf16x8*)(W2ENh + off);
    const bf16x8 a1 = *(const bf16x8*)(W2ENh + 1572864 + off);
    bf16x8 ov;
#pragma unroll
    for (int i = 0; i < 8; ++i)
      ov[i] = (short)f2bf(bf2f((unsigned short)a0[i]) + bf2f((unsigned short)a1[i]));
    *(bf16x8*)(W2EN + off) = ov;
  }
}

// ---------------------------------------------------------------------------
// combine2: one block per batch row b. Stage EN0[b] (15 x 691 f32) in LDS,
// emit both outputs with coalesced writes (incl. out1's (v*15+i) order).
// ---------------------------------------------------------------------------
__global__ __launch_bounds__(256) void combine2_k(const float* __restrict__ EN0,
                                                  const float* __restrict__ b_emb,
                                                  const float* __restrict__ b_node,
                                                  float* __restrict__ out0,
                                                  float* __restrict__ out1) {
  __shared__ float lds[15 * 691];
  const int b = blockIdx.x, tid = threadIdx.x;
  for (int f = tid; f < 15 * 691; f += 256) {
    const int j = f / 691, col = f - j * 691;
    lds[f] = EN0[((size_t)(j * 512 + b)) * 768 + col];
  }
  __syncthreads();
  const unsigned long long PACK = 0x0FEDB7CA69538421ULL;  // MSK[i] nibbles
  // out0: (b, i, col<300)
  for (int f = tid; f < 15 * 300; f += 256) {
    const int i = f / 300, col = f - i * 300;
    const unsigned mi = (unsigned)(PACK >> (4 * i)) & 15u;
    float sum = b_emb[col];
#pragma unroll
    for (int j = 0; j < 15; ++j) {
      const unsigned mj = (unsigned)(PACK >> (4 * j)) & 15u;
      if ((mj & mi) == mj) sum += lds[j * 691 + col];
    }
    out0[((size_t)b * 15 + i) * 300 + col] = sum;
  }
  // out1: (b, v, i) flat — coalesced
  for (int f = tid; f < 391 * 15; f += 256) {
    const int v = f / 15, i = f - v * 15;
    const unsigned mi = (unsigned)(PACK >> (4 * i)) & 15u;
    float sum = b_node[v];
#pragma unroll
    for (int j = 0; j < 15; ++j) {
      const unsigned mj = (unsigned)(PACK >> (4 * j)) & 15u;
      if ((mj & mi) == mj) sum += lds[j * 691 + 300 + v];
    }
    out1[((size_t)b * 391 + v) * 15 + i] = sum;
  }
}

// ---------------------------------------------------------------------------
extern "C" void kernel_launch(void* const* d_in, const int* in_sizes, int n_in,
                              void* d_out, int out_size, void* d_ws, size_t ws_size,
                              hipStream_t stream) {
  const float* x     = (const float*)d_in[0];
  const float* w11   = (const float*)d_in[1];
  const float* b11   = (const float*)d_in[2];
  const float* w21   = (const float*)d_in[3];
  const float* b21   = (const float*)d_in[4];
  const float* w12   = (const float*)d_in[5];
  const float* b12   = (const float*)d_in[6];
  const float* w22   = (const float*)d_in[7];
  const float* b22   = (const float*)d_in[8];
  const float* w13   = (const float*)d_in[9];
  const float* b13   = (const float*)d_in[10];
  const float* w23   = (const float*)d_in[11];
  const float* b23   = (const float*)d_in[12];
  const float* w14   = (const float*)d_in[13];
  const float* b14   = (const float*)d_in[14];
  const float* w24   = (const float*)d_in[15];
  const float* b24   = (const float*)d_in[16];
  const float* wemb  = (const float*)d_in[17];
  const float* bemb  = (const float*)d_in[18];
  const float* wnode = (const float*)d_in[19];
  const float* bnode = (const float*)d_in[20];

  char* ws = (char*)d_ws;
  // layout (bytes); EN0 aliases xrb+w1cat (dead after mega1). peak ~79.2 MB
  unsigned short* xrb   = (unsigned short*)(ws + 0);                 //  8,388,608
  unsigned short* w1cat = (unsigned short*)(ws + 8388608);           // -> 29,360,128
  unsigned short* w2t   = (unsigned short*)(ws + 29360128);          // -> 37,748,736
  unsigned short* wen   = (unsigned short*)(ws + 37748736);          // -> 40,894,464
  unsigned short* H0h   = (unsigned short*)(ws + 40894464);          // 2x10,485,760 -> 61,865,984
  unsigned short* W2ENh = (unsigned short*)(ws + 61865984);          // 2x 3,145,728 -> 68,157,440
  unsigned short* W2EN  = (unsigned short*)(ws + 68157440);          // -> 71,303,168
  float*          ENb   = (float*)(ws + 71303168);                   // -> 71,315,456
  unsigned short* h1bf  = (unsigned short*)(ws + 71315456);          // -> 79,179,776
  float*          EN0   = (float*)(ws + 0);                          // 23,592,960 (aliases xrb/w1cat)

  float* out0 = (float*)d_out;            // embeddings (512,15,300)
  float* out1 = out0 + 2304000;           // node_out^T (512,391,15)

  prep_all_k<<<17664, 256, 0, stream>>>(x, w11, w12, w13, w14, w21, w22, w23, w24,
                                        wemb, wnode, b21, b22, b23, b24,
                                        xrb, w1cat, w2t, wen, ENb);
  mega1_k   <<<832, 256, 0, stream>>>(xrb, w1cat, wen, w2t, H0h, W2ENh);
  post1_k   <<<9216, 128, 0, stream>>>(H0h, h1bf, b11, b12, b13, b14, W2ENh, W2EN);
  gemmF_k   <<<dim3(6, 60), 256, 0, stream>>>(h1bf, W2EN, ENb, EN0);
  combine2_k<<<512, 256, 0, stream>>>(EN0, bemb, bnode, out0, out1);
}

// Round 7
// 139.339 us; speedup vs baseline: 1.0239x; 1.0239x over previous
//
#include <hip/hip_runtime.h>
#include <stdint.h>

using bf16x8 = __attribute__((ext_vector_type(8))) short;
using f32x4  = __attribute__((ext_vector_type(4))) float;

#define DEVINL __device__ __forceinline__

DEVINL unsigned short f2bf(float f) {
  union { float f; unsigned u; } v; v.f = f;
  unsigned u = v.u;
  return (unsigned short)((u + 0x7FFFu + ((u >> 16) & 1u)) >> 16);
}
DEVINL float bf2f(unsigned short h) {
  union { unsigned u; float f; } v; v.u = ((unsigned)h) << 16;
  return v.f;
}

DEVINL void gload_lds16(const void* g, void* l) {
  __builtin_amdgcn_global_load_lds(
      (const __attribute__((address_space(1))) void*)g,
      (__attribute__((address_space(3))) void*)l, 16, 0, 0);
}

// ---------------------------------------------------------------------------
// Pipelined 128x128 bf16 GEMM tile: m97 fragment layout + double-buffered LDS
// with raw s_barrier and counted vmcnt(8) so next-tile global_load_lds stays
// in flight across the barrier (T4; needed because co-residency is ~1.3
// blocks/CU at this grid size, so cross-block overlap can't hide the drain).
// A (row-major bf16, ld=K), B (row-major bf16, ld=K), C = A·B^T (+bias).
// ---------------------------------------------------------------------------
template<int OUT_BF16, int HAS_BIAS>
DEVINL void gemm_core(const unsigned short* __restrict__ A,
                      const unsigned short* __restrict__ B,
                      void* __restrict__ C,
                      const float* __restrict__ bias,
                      int K, int Cld, int arow0, int brow0, int crow0, int ccol0)
{
  __shared__ __align__(16) unsigned short As[2][128 * 64];
  __shared__ __align__(16) unsigned short Bs[2][128 * 64];

  const int t    = threadIdx.x;
  const int wave = t >> 6;
  const int lane = t & 63;
  const int wr   = (wave >> 1) << 6;   // 0 or 64
  const int wc   = (wave & 1) << 6;    // 0 or 64
  const int lrow = lane & 15;
  const int kg   = lane >> 4;          // 0..3

  f32x4 acc[4][4];
#pragma unroll
  for (int r = 0; r < 4; ++r)
#pragma unroll
    for (int q = 0; q < 4; ++q) acc[r][q] = (f32x4){0.f, 0.f, 0.f, 0.f};

  // staging: LDS row-major [128][64]; wave-uniform dst + lane*16 (gload_lds rule)
  const int srow = t >> 3;             // 0..31 (pass p adds p*32)
  const int scol = (t & 7) << 3;       // bf16 element offset (16B granules)
  const unsigned short* aSrc = A + (size_t)(arow0 + srow) * K + scol;
  const unsigned short* bSrc = B + (size_t)(brow0 + srow) * K + scol;

  const int nt = K >> 6;
  {  // prologue: stage tile 0 -> buffer 0 (8 gload_lds per wave)
    char* aD = (char*)As[0] + wave * 1024;
    char* bD = (char*)Bs[0] + wave * 1024;
#pragma unroll
    for (int p = 0; p < 4; ++p) {
      gload_lds16(aSrc + (size_t)(p * 32) * K, aD + p * 4096);
      gload_lds16(bSrc + (size_t)(p * 32) * K, bD + p * 4096);
    }
  }
  int cur = 0;
  for (int tt = 0; tt < nt; ++tt) {
    if (tt + 1 < nt) {                 // issue next tile's 8 loads, then wait
      const int k0 = (tt + 1) << 6;    // for the PREVIOUS 8 only (counted)
      char* aD = (char*)As[cur ^ 1] + wave * 1024;
      char* bD = (char*)Bs[cur ^ 1] + wave * 1024;
#pragma unroll
      for (int p = 0; p < 4; ++p) {
        gload_lds16(aSrc + (size_t)(p * 32) * K + k0, aD + p * 4096);
        gload_lds16(bSrc + (size_t)(p * 32) * K + k0, bD + p * 4096);
      }
      asm volatile("s_waitcnt vmcnt(8)" ::: "memory");
    } else {
      asm volatile("s_waitcnt vmcnt(0)" ::: "memory");
    }
    asm volatile("s_barrier" ::: "memory");   // raw: no compiler vmcnt(0) drain
    const unsigned short* Ab = As[cur];
    const unsigned short* Bb = Bs[cur];
#pragma unroll
    for (int kk = 0; kk < 64; kk += 32) {
      bf16x8 af[4], bq[4];
#pragma unroll
      for (int r = 0; r < 4; ++r)
        af[r] = *(const bf16x8*)&Ab[(wr + r * 16 + lrow) * 64 + kk + kg * 8];
#pragma unroll
      for (int q = 0; q < 4; ++q)
        bq[q] = *(const bf16x8*)&Bb[(wc + q * 16 + lrow) * 64 + kk + kg * 8];
#pragma unroll
      for (int r = 0; r < 4; ++r)
#pragma unroll
        for (int q = 0; q < 4; ++q)
          acc[r][q] = __builtin_amdgcn_mfma_f32_16x16x32_bf16(af[r], bq[q], acc[r][q], 0, 0, 0);
    }
    // all this wave's ds_reads are consumed (=> complete) before this barrier;
    // barrier makes that global before next iteration overwrites buf[cur^1].
    asm volatile("s_barrier" ::: "memory");
    cur ^= 1;
  }

  // epilogue: C/D layout col=lane&15, row=(lane>>4)*4+v  [m89/m91 verified]
#pragma unroll
  for (int r = 0; r < 4; ++r) {
#pragma unroll
    for (int q = 0; q < 4; ++q) {
      const int col = ccol0 + wc + q * 16 + lrow;
      const float bv = HAS_BIAS ? bias[col] : 0.f;
#pragma unroll
      for (int v = 0; v < 4; ++v) {
        const int row = crow0 + wr + r * 16 + (kg << 2) + v;
        const float val = acc[r][q][v] + bv;
        if (OUT_BF16)
          ((unsigned short*)C)[(size_t)row * Cld + col] = f2bf(val);
        else
          ((float*)C)[(size_t)row * Cld + col] = val;
      }
    }
  }
}

// ---------------------------------------------------------------------------
// mega1: blocks 0..319  -> H0p[p] = XR[m(p)] @ w1cat[j(p)]^T   (20 pairs x 16 tiles)
//        blocks 320..415 -> W2EN_s = WEN @ w2t_s^T             (4 s x 24 tiles)
// ---------------------------------------------------------------------------
__global__ __launch_bounds__(256) void mega1_k(const unsigned short* __restrict__ xrb,
                                               const unsigned short* __restrict__ w1cat,
                                               const unsigned short* __restrict__ wen,
                                               const unsigned short* __restrict__ w2t,
                                               unsigned short* __restrict__ H0p,
                                               unsigned short* __restrict__ W2EN) {
  const int bid = blockIdx.x;
  if (bid < 320) {
    const int p = bid >> 4, q = bid & 15;
    const int rt = q >> 2, ct = q & 3;
    const int MM[20] = {0,1,2,3, 0,1,2, 1,2,3, 0,1, 1,2, 2,3, 0,1,2,3};
    const int JJ[20] = {0,0,0,0, 1,1,1, 2,2,2, 3,3, 4,4, 5,5, 6,7,8,9};
    gemm_core<1, 0>(xrb, w1cat, H0p, nullptr, 2048, 512,
                    MM[p] * 512 + rt * 128, JJ[p] * 512 + ct * 128,
                    p * 512 + rt * 128, ct * 128);
  } else {
    const int b2 = bid - 320;
    const int s = b2 / 24, r = b2 % 24;
    const int rt = r >> 2, ct = r & 3;       // rt 0..5 (768 rows), ct 0..3 (512 cols)
    gemm_core<1, 0>(wen, w2t, W2EN, nullptr, 2048, 512,
                    rt * 128, s * 512 + ct * 128,
                    s * 768 + rt * 128, ct * 128);
  }
}

// gemmF: EN0 = h1(7680x512) @ W2EN_s^T + ENb_s   (fp32 out, 768 cols)
__global__ __launch_bounds__(256) void gemmF_k(const unsigned short* __restrict__ h1,
                                               const unsigned short* __restrict__ W2EN,
                                               const float* __restrict__ ENb,
                                               float* __restrict__ EN0) {
  const int y = blockIdx.y;                  // 0..59 row tiles
  const int c = y >> 2;
  const int s = (c < 4) ? 1 : (c < 10) ? 2 : (c < 14) ? 3 : 4;
  gemm_core<0, 1>(h1, W2EN, EN0, ENb + (size_t)(s - 1) * 768, 512, 768,
                  y * 128, (s - 1) * 768 + blockIdx.x * 128,
                  y * 128, blockIdx.x * 128);
}

// ---------------------------------------------------------------------------
// prep kernels (round-5 proven versions, kept separate)
// ---------------------------------------------------------------------------
__global__ __launch_bounds__(256) void prep_xr(const float* __restrict__ x,
                                               unsigned short* __restrict__ xrb) {
  const int tid = blockIdx.x * 256 + threadIdx.x;   // 1,048,576
  const int r = tid >> 9;                           // row = m*512+b
  const int k = (tid & 511) << 2;
  const int m = r >> 9, b = r & 511;
  const float4 vv = *(const float4*)(x + ((size_t)(b * 4 + m)) * 2048 + k);
  ushort4 o;
  o.x = f2bf(fmaxf(vv.x, 0.f)); o.y = f2bf(fmaxf(vv.y, 0.f));
  o.z = f2bf(fmaxf(vv.z, 0.f)); o.w = f2bf(fmaxf(vv.w, 0.f));
  *(ushort4*)(xrb + (size_t)r * 2048 + k) = o;
}

__global__ __launch_bounds__(256) void prep_w1cat(const float* w11, const float* w12,
                                                  const float* w13, const float* w14,
                                                  unsigned short* __restrict__ w1cat) {
  const int tid = blockIdx.x * 256 + threadIdx.x;   // 2,621,440
  const int r = tid >> 9;                           // 0..5119 = j*512+o
  const int k = (tid & 511) << 2;
  const int j = r >> 9, o = r & 511;
  const float* src; int s, tt;
  if (j == 0)      { src = w11; s = 1; tt = 0; }
  else if (j < 3)  { src = w12; s = 2; tt = j - 1; }
  else if (j < 6)  { src = w13; s = 3; tt = j - 3; }
  else             { src = w14; s = 4; tt = j - 6; }
  const float4 vv = *(const float4*)(src + (size_t)o * (s * 2048) + tt * 2048 + k);
  ushort4 ov;
  ov.x = f2bf(vv.x); ov.y = f2bf(vv.y); ov.z = f2bf(vv.z); ov.w = f2bf(vv.w);
  *(ushort4*)(w1cat + (size_t)r * 2048 + k) = ov;
}

// transpose w2_s (2048 x 512 f32) -> w2t[s] (512 x 2048 bf16), 64x64 LDS tiles
__global__ __launch_bounds__(256) void prep_w2t(const float* w21, const float* w22,
                                                const float* w23, const float* w24,
                                                unsigned short* __restrict__ w2t) {
  __shared__ float lds[64][65];
  const int s = blockIdx.z, rt = blockIdx.y, ct = blockIdx.x;  // rt: o2/64 (32), ct: d/64 (8)
  const float* src = (s == 0) ? w21 : (s == 1) ? w22 : (s == 2) ? w23 : w24;
  const int tr = threadIdx.x >> 4;            // 0..15
  const int tc = (threadIdx.x & 15) << 2;     // 0..60
#pragma unroll
  for (int i = 0; i < 4; ++i) {
    const float4 v = *(const float4*)(src + (size_t)(rt * 64 + tr + 16 * i) * 512 + ct * 64 + tc);
    lds[tr + 16 * i][tc + 0] = v.x; lds[tr + 16 * i][tc + 1] = v.y;
    lds[tr + 16 * i][tc + 2] = v.z; lds[tr + 16 * i][tc + 3] = v.w;
  }
  __syncthreads();
#pragma unroll
  for (int i = 0; i < 4; ++i) {
    ushort4 ov;
    ov.x = f2bf(lds[tc + 0][tr + 16 * i]); ov.y = f2bf(lds[tc + 1][tr + 16 * i]);
    ov.z = f2bf(lds[tc + 2][tr + 16 * i]); ov.w = f2bf(lds[tc + 3][tr + 16 * i]);
    *(ushort4*)(w2t + ((size_t)s * 512 + ct * 64 + tr + 16 * i) * 2048 + rt * 64 + tc) = ov;
  }
}

__global__ __launch_bounds__(256) void prep_wen(const float* __restrict__ w_emb,
                                                const float* __restrict__ w_node,
                                                unsigned short* __restrict__ wen) {
  const int tid = blockIdx.x * 256 + threadIdx.x;   // 393,216
  const int r = tid >> 9;                           // 0..767
  const int k = (tid & 511) << 2;
  float4 vv = make_float4(0.f, 0.f, 0.f, 0.f);
  if (r < 300)       vv = *(const float4*)(w_emb + (size_t)r * 2048 + k);
  else if (r < 691)  vv = *(const float4*)(w_node + (size_t)(r - 300) * 2048 + k);
  ushort4 ov;
  ov.x = f2bf(vv.x); ov.y = f2bf(vv.y); ov.z = f2bf(vv.z); ov.w = f2bf(vv.w);
  *(ushort4*)(wen + (size_t)r * 2048 + k) = ov;
}

// ENb[s][e] = dot(WEN_row_e (f32 sources), b2_s)  — one wave per output
__global__ __launch_bounds__(256) void prep_enb(const float* __restrict__ wemb,
                                                const float* __restrict__ wnode,
                                                const float* b21, const float* b22,
                                                const float* b23, const float* b24,
                                                float* __restrict__ ENb) {
  const int w = blockIdx.x * 4 + (threadIdx.x >> 6);   // 0..3071
  const int lane = threadIdx.x & 63;
  const int s = w / 768, e = w % 768;
  const float* b2 = (s == 0) ? b21 : (s == 1) ? b22 : (s == 2) ? b23 : b24;
  float acc = 0.f;
  if (e < 691) {
    const float* row = (e < 300) ? (wemb + (size_t)e * 2048) : (wnode + (size_t)(e - 300) * 2048);
#pragma unroll
    for (int i = 0; i < 8; ++i) {
      const float4 a  = *(const float4*)(row + i * 256 + lane * 4);
      const float4 bb = *(const float4*)(b2  + i * 256 + lane * 4);
      acc += a.x * bb.x + a.y * bb.y + a.z * bb.z + a.w * bb.w;
    }
  }
#pragma unroll
  for (int off = 32; off; off >>= 1) acc += __shfl_down(acc, off);
  if (lane == 0) ENb[w] = acc;
}

// combine1: h1[c*512+b, o] = relu(b1_s[o] + sum_t H0p[P[c][t]*512 + b, o]) -> bf16
__global__ __launch_bounds__(128) void combine1_k(const unsigned short* __restrict__ H0p,
                                                  unsigned short* __restrict__ h1,
                                                  const float* __restrict__ b11,
                                                  const float* __restrict__ b12,
                                                  const float* __restrict__ b13,
                                                  const float* __restrict__ b14) {
  const int cb = blockIdx.x;            // 0..7679 = c*512+b
  const int c = cb >> 9, b = cb & 511;
  const int s = (c < 4) ? 1 : (c < 10) ? 2 : (c < 14) ? 3 : 4;
  const unsigned char P[15][4] = {
    {0,0,0,0},{1,0,0,0},{2,0,0,0},{3,0,0,0},
    {4,7,0,0},{4,8,0,0},{4,9,0,0},{5,8,0,0},{5,9,0,0},{6,9,0,0},
    {10,12,14,0},{10,12,15,0},{10,13,15,0},{11,13,15,0},
    {16,17,18,19}};
  const float* b1 = (s == 1) ? b11 : (s == 2) ? b12 : (s == 3) ? b13 : b14;
  const int o = threadIdx.x << 2;
  float4 a = *(const float4*)(b1 + o);
  for (int t = 0; t < s; ++t) {
    const int p = P[c][t];
    const ushort4 hv = *(const ushort4*)(H0p + ((size_t)(p * 512 + b)) * 512 + o);
    a.x += bf2f(hv.x); a.y += bf2f(hv.y); a.z += bf2f(hv.z); a.w += bf2f(hv.w);
  }
  ushort4 ov;
  ov.x = f2bf(fmaxf(a.x, 0.f)); ov.y = f2bf(fmaxf(a.y, 0.f));
  ov.z = f2bf(fmaxf(a.z, 0.f)); ov.w = f2bf(fmaxf(a.w, 0.f));
  *(ushort4*)(h1 + (size_t)cb * 512 + o) = ov;
}

// ---------------------------------------------------------------------------
// combine2: one block per batch row b. Stage EN0[b] (15 x 691 f32) in LDS,
// emit both outputs with coalesced writes (incl. out1's (v*15+i) order).
// ---------------------------------------------------------------------------
__global__ __launch_bounds__(256) void combine2_k(const float* __restrict__ EN0,
                                                  const float* __restrict__ b_emb,
                                                  const float* __restrict__ b_node,
                                                  float* __restrict__ out0,
                                                  float* __restrict__ out1) {
  __shared__ float lds[15 * 691];
  const int b = blockIdx.x, tid = threadIdx.x;
  for (int f = tid; f < 15 * 691; f += 256) {
    const int j = f / 691, col = f - j * 691;
    lds[f] = EN0[((size_t)(j * 512 + b)) * 768 + col];
  }
  __syncthreads();
  const unsigned long long PACK = 0x0FEDB7CA69538421ULL;  // MSK[i] nibbles
  // out0: (b, i, col<300)
  for (int f = tid; f < 15 * 300; f += 256) {
    const int i = f / 300, col = f - i * 300;
    const unsigned mi = (unsigned)(PACK >> (4 * i)) & 15u;
    float sum = b_emb[col];
#pragma unroll
    for (int j = 0; j < 15; ++j) {
      const unsigned mj = (unsigned)(PACK >> (4 * j)) & 15u;
      if ((mj & mi) == mj) sum += lds[j * 691 + col];
    }
    out0[((size_t)b * 15 + i) * 300 + col] = sum;
  }
  // out1: (b, v, i) flat — coalesced
  for (int f = tid; f < 391 * 15; f += 256) {
    const int v = f / 15, i = f - v * 15;
    const unsigned mi = (unsigned)(PACK >> (4 * i)) & 15u;
    float sum = b_node[v];
#pragma unroll
    for (int j = 0; j < 15; ++j) {
      const unsigned mj = (unsigned)(PACK >> (4 * j)) & 15u;
      if ((mj & mi) == mj) sum += lds[j * 691 + 300 + v];
    }
    out1[((size_t)b * 391 + v) * 15 + i] = sum;
  }
}

// ---------------------------------------------------------------------------
extern "C" void kernel_launch(void* const* d_in, const int* in_sizes, int n_in,
                              void* d_out, int out_size, void* d_ws, size_t ws_size,
                              hipStream_t stream) {
  const float* x     = (const float*)d_in[0];
  const float* w11   = (const float*)d_in[1];
  const float* b11   = (const float*)d_in[2];
  const float* w21   = (const float*)d_in[3];
  const float* b21   = (const float*)d_in[4];
  const float* w12   = (const float*)d_in[5];
  const float* b12   = (const float*)d_in[6];
  const float* w22   = (const float*)d_in[7];
  const float* b22   = (const float*)d_in[8];
  const float* w13   = (const float*)d_in[9];
  const float* b13   = (const float*)d_in[10];
  const float* w23   = (const float*)d_in[11];
  const float* b23   = (const float*)d_in[12];
  const float* w14   = (const float*)d_in[13];
  const float* b14   = (const float*)d_in[14];
  const float* w24   = (const float*)d_in[15];
  const float* b24   = (const float*)d_in[16];
  const float* wemb  = (const float*)d_in[17];
  const float* bemb  = (const float*)d_in[18];
  const float* wnode = (const float*)d_in[19];
  const float* bnode = (const float*)d_in[20];

  char* ws = (char*)d_ws;
  // layout (bytes); EN0 aliases xrb+w1cat (dead after mega1). peak ~62.4 MB
  unsigned short* xrb   = (unsigned short*)(ws + 0);                 //  8,388,608
  unsigned short* w1cat = (unsigned short*)(ws + 8388608);           // 20,971,520 -> 29,360,128
  unsigned short* w2t   = (unsigned short*)(ws + 29360128);          //  8,388,608 -> 37,748,736
  unsigned short* wen   = (unsigned short*)(ws + 37748736);          //  3,145,728 -> 40,894,464
  unsigned short* H0p   = (unsigned short*)(ws + 40894464);          // 10,485,760 -> 51,380,224
  unsigned short* W2EN  = (unsigned short*)(ws + 51380224);          //  3,145,728 -> 54,525,952
  float*          ENb   = (float*)(ws + 54525952);                   //     12,288 -> 54,538,240
  unsigned short* h1bf  = (unsigned short*)(ws + 54538240);          //  7,864,320 -> 62,402,560
  float*          EN0   = (float*)(ws + 0);                          // 23,592,960 (aliases xrb/w1cat)

  float* out0 = (float*)d_out;            // embeddings (512,15,300)
  float* out1 = out0 + 2304000;           // node_out^T (512,391,15)

  prep_xr   <<<4096, 256, 0, stream>>>(x, xrb);
  prep_w1cat<<<10240, 256, 0, stream>>>(w11, w12, w13, w14, w1cat);
  prep_w2t  <<<dim3(8, 32, 4), 256, 0, stream>>>(w21, w22, w23, w24, w2t);
  prep_wen  <<<1536, 256, 0, stream>>>(wemb, wnode, wen);
  prep_enb  <<<768, 256, 0, stream>>>(wemb, wnode, b21, b22, b23, b24, ENb);

  mega1_k   <<<416, 256, 0, stream>>>(xrb, w1cat, wen, w2t, H0p, W2EN);
  combine1_k<<<7680, 128, 0, stream>>>(H0p, h1bf, b11, b12, b13, b14);
  gemmF_k   <<<dim3(6, 60), 256, 0, stream>>>(h1bf, W2EN, ENb, EN0);
  combine2_k<<<512, 256, 0, stream>>>(EN0, bemb, bnode, out0, out1);
}

// Round 8
// 103.113 us; speedup vs baseline: 1.3836x; 1.3513x over previous
//
#include <hip/hip_runtime.h>
#include <stdint.h>

using bf16x8 = __attribute__((ext_vector_type(8))) short;
using f32x4  = __attribute__((ext_vector_type(4))) float;

#define DEVINL __device__ __forceinline__

DEVINL unsigned short f2bf(float f) {
  union { float f; unsigned u; } v; v.f = f;
  unsigned u = v.u;
  return (unsigned short)((u + 0x7FFFu + ((u >> 16) & 1u)) >> 16);
}
DEVINL float bf2f(unsigned short h) {
  union { unsigned u; float f; } v; v.u = ((unsigned)h) << 16;
  return v.f;
}

DEVINL void gload_lds16(const void* g, void* l) {
  __builtin_amdgcn_global_load_lds(
      (const __attribute__((address_space(1))) void*)g,
      (__attribute__((address_space(3))) void*)l, 16, 0, 0);
}

// ---------------------------------------------------------------------------
// Pipelined 128x128 bf16 GEMM tile with T2 XOR-swizzled LDS:
//  - LDS dest stays LINEAR (global_load_lds rule); the swizzle is applied by
//    permuting each lane's GLOBAL source 16B-chunk: chunk_phys = chunk ^ (row&7)
//    (permutation within a 128B segment -> coalescing preserved).
//  - ds_read fetches chunk (kg + kk/8) at physical chunk ((kg+kk/8) ^ (row&7)).
//    Post-swizzle every bank serves exactly 8 lane-accesses per b128 = minimum.
//  - double-buffered, raw s_barrier + counted vmcnt(8) (no full drain).
// A (row-major bf16, ld=K), B (row-major bf16, ld=K), C = A·B^T (+bias).
// ---------------------------------------------------------------------------
template<int OUT_BF16, int HAS_BIAS>
DEVINL void gemm_core(const unsigned short* __restrict__ A,
                      const unsigned short* __restrict__ B,
                      void* __restrict__ C,
                      const float* __restrict__ bias,
                      int K, int Cld, int arow0, int brow0, int crow0, int ccol0)
{
  __shared__ __align__(16) unsigned short As[2][128 * 64];
  __shared__ __align__(16) unsigned short Bs[2][128 * 64];

  const int t    = threadIdx.x;
  const int wave = t >> 6;
  const int lane = t & 63;
  const int wr   = (wave >> 1) << 6;   // 0 or 64
  const int wc   = (wave & 1) << 6;    // 0 or 64
  const int lrow = lane & 15;
  const int kg   = lane >> 4;          // 0..3

  f32x4 acc[4][4];
#pragma unroll
  for (int r = 0; r < 4; ++r)
#pragma unroll
    for (int q = 0; q < 4; ++q) acc[r][q] = (f32x4){0.f, 0.f, 0.f, 0.f};

  // staging with pre-swizzled global source column (16B chunks within 128B row)
  const int srow = t >> 3;                                  // 0..31 (pass p adds p*32; 32%8==0)
  const int scol = (((t & 7) ^ ((t >> 3) & 7)) << 3);       // swizzled source chunk
  const unsigned short* aSrc = A + (size_t)(arow0 + srow) * K + scol;
  const unsigned short* bSrc = B + (size_t)(brow0 + srow) * K + scol;

  const int nt = K >> 6;
  {  // prologue: stage tile 0 -> buffer 0
    char* aD = (char*)As[0] + wave * 1024;
    char* bD = (char*)Bs[0] + wave * 1024;
#pragma unroll
    for (int p = 0; p < 4; ++p) {
      gload_lds16(aSrc + (size_t)(p * 32) * K, aD + p * 4096);
      gload_lds16(bSrc + (size_t)(p * 32) * K, bD + p * 4096);
    }
  }
  // swizzled read chunk offsets (elements): chunk = (kg + kk/8) ^ (row&7)
  const int rs = lrow & 7;
  const int cA0 = ((kg + 0) ^ rs) << 3;   // kk = 0
  const int cA1 = ((kg + 4) ^ rs) << 3;   // kk = 32

  int cur = 0;
  for (int tt = 0; tt < nt; ++tt) {
    if (tt + 1 < nt) {
      const int k0 = (tt + 1) << 6;
      char* aD = (char*)As[cur ^ 1] + wave * 1024;
      char* bD = (char*)Bs[cur ^ 1] + wave * 1024;
#pragma unroll
      for (int p = 0; p < 4; ++p) {
        gload_lds16(aSrc + (size_t)(p * 32) * K + k0, aD + p * 4096);
        gload_lds16(bSrc + (size_t)(p * 32) * K + k0, bD + p * 4096);
      }
      asm volatile("s_waitcnt vmcnt(8)" ::: "memory");
    } else {
      asm volatile("s_waitcnt vmcnt(0)" ::: "memory");
    }
    asm volatile("s_barrier" ::: "memory");
    const unsigned short* Ab = As[cur];
    const unsigned short* Bb = Bs[cur];
#pragma unroll
    for (int kk = 0; kk < 64; kk += 32) {
      const int cofs = (kk == 0) ? cA0 : cA1;
      bf16x8 af[4], bq[4];
#pragma unroll
      for (int r = 0; r < 4; ++r)
        af[r] = *(const bf16x8*)&Ab[(wr + r * 16 + lrow) * 64 + cofs];
#pragma unroll
      for (int q = 0; q < 4; ++q)
        bq[q] = *(const bf16x8*)&Bb[(wc + q * 16 + lrow) * 64 + cofs];
#pragma unroll
      for (int r = 0; r < 4; ++r)
#pragma unroll
        for (int q = 0; q < 4; ++q)
          acc[r][q] = __builtin_amdgcn_mfma_f32_16x16x32_bf16(af[r], bq[q], acc[r][q], 0, 0, 0);
    }
    asm volatile("s_barrier" ::: "memory");
    cur ^= 1;
  }

  // epilogue: C/D layout col=lane&15, row=(lane>>4)*4+v  [m89/m91 verified]
#pragma unroll
  for (int r = 0; r < 4; ++r) {
#pragma unroll
    for (int q = 0; q < 4; ++q) {
      const int col = ccol0 + wc + q * 16 + lrow;
      const float bv = HAS_BIAS ? bias[col] : 0.f;
#pragma unroll
      for (int v = 0; v < 4; ++v) {
        const int row = crow0 + wr + r * 16 + (kg << 2) + v;
        const float val = acc[r][q][v] + bv;
        if (OUT_BF16)
          ((unsigned short*)C)[(size_t)row * Cld + col] = f2bf(val);
        else
          ((float*)C)[(size_t)row * Cld + col] = val;
      }
    }
  }
}

// ---------------------------------------------------------------------------
// mega1: blocks 0..319  -> H0p[p] = XR[m(p)] @ w1cat[j(p)]^T   (20 pairs x 16 tiles)
//        blocks 320..415 -> W2EN_s = WEN @ w2t_s^T             (4 s x 24 tiles)
// ---------------------------------------------------------------------------
__global__ __launch_bounds__(256) void mega1_k(const unsigned short* __restrict__ xrb,
                                               const unsigned short* __restrict__ w1cat,
                                               const unsigned short* __restrict__ wen,
                                               const unsigned short* __restrict__ w2t,
                                               unsigned short* __restrict__ H0p,
                                               unsigned short* __restrict__ W2EN) {
  const int bid = blockIdx.x;
  if (bid < 320) {
    const int p = bid >> 4, q = bid & 15;
    const int rt = q >> 2, ct = q & 3;
    const int MM[20] = {0,1,2,3, 0,1,2, 1,2,3, 0,1, 1,2, 2,3, 0,1,2,3};
    const int JJ[20] = {0,0,0,0, 1,1,1, 2,2,2, 3,3, 4,4, 5,5, 6,7,8,9};
    gemm_core<1, 0>(xrb, w1cat, H0p, nullptr, 2048, 512,
                    MM[p] * 512 + rt * 128, JJ[p] * 512 + ct * 128,
                    p * 512 + rt * 128, ct * 128);
  } else {
    const int b2 = bid - 320;
    const int s = b2 / 24, r = b2 % 24;
    const int rt = r >> 2, ct = r & 3;       // rt 0..5 (768 rows), ct 0..3 (512 cols)
    gemm_core<1, 0>(wen, w2t, W2EN, nullptr, 2048, 512,
                    rt * 128, s * 512 + ct * 128,
                    s * 768 + rt * 128, ct * 128);
  }
}

// gemmF: EN0 = h1(7680x512) @ W2EN_s^T + ENb_s   (fp32 out, 768 cols)
__global__ __launch_bounds__(256) void gemmF_k(const unsigned short* __restrict__ h1,
                                               const unsigned short* __restrict__ W2EN,
                                               const float* __restrict__ ENb,
                                               float* __restrict__ EN0) {
  const int y = blockIdx.y;                  // 0..59 row tiles
  const int c = y >> 2;
  const int s = (c < 4) ? 1 : (c < 10) ? 2 : (c < 14) ? 3 : 4;
  gemm_core<0, 1>(h1, W2EN, EN0, ENb + (size_t)(s - 1) * 768, 512, 768,
                  y * 128, (s - 1) * 768 + blockIdx.x * 128,
                  y * 128, blockIdx.x * 128);
}

// ---------------------------------------------------------------------------
// prep kernels (round-5 proven versions)
// ---------------------------------------------------------------------------
__global__ __launch_bounds__(256) void prep_xr(const float* __restrict__ x,
                                               unsigned short* __restrict__ xrb) {
  const int tid = blockIdx.x * 256 + threadIdx.x;   // 1,048,576
  const int r = tid >> 9;                           // row = m*512+b
  const int k = (tid & 511) << 2;
  const int m = r >> 9, b = r & 511;
  const float4 vv = *(const float4*)(x + ((size_t)(b * 4 + m)) * 2048 + k);
  ushort4 o;
  o.x = f2bf(fmaxf(vv.x, 0.f)); o.y = f2bf(fmaxf(vv.y, 0.f));
  o.z = f2bf(fmaxf(vv.z, 0.f)); o.w = f2bf(fmaxf(vv.w, 0.f));
  *(ushort4*)(xrb + (size_t)r * 2048 + k) = o;
}

__global__ __launch_bounds__(256) void prep_w1cat(const float* w11, const float* w12,
                                                  const float* w13, const float* w14,
                                                  unsigned short* __restrict__ w1cat) {
  const int tid = blockIdx.x * 256 + threadIdx.x;   // 2,621,440
  const int r = tid >> 9;                           // 0..5119 = j*512+o
  const int k = (tid & 511) << 2;
  const int j = r >> 9, o = r & 511;
  const float* src; int s, tt;
  if (j == 0)      { src = w11; s = 1; tt = 0; }
  else if (j < 3)  { src = w12; s = 2; tt = j - 1; }
  else if (j < 6)  { src = w13; s = 3; tt = j - 3; }
  else             { src = w14; s = 4; tt = j - 6; }
  const float4 vv = *(const float4*)(src + (size_t)o * (s * 2048) + tt * 2048 + k);
  ushort4 ov;
  ov.x = f2bf(vv.x); ov.y = f2bf(vv.y); ov.z = f2bf(vv.z); ov.w = f2bf(vv.w);
  *(ushort4*)(w1cat + (size_t)r * 2048 + k) = ov;
}

// transpose w2_s (2048 x 512 f32) -> w2t[s] (512 x 2048 bf16), 64x64 LDS tiles
__global__ __launch_bounds__(256) void prep_w2t(const float* w21, const float* w22,
                                                const float* w23, const float* w24,
                                                unsigned short* __restrict__ w2t) {
  __shared__ float lds[64][65];
  const int s = blockIdx.z, rt = blockIdx.y, ct = blockIdx.x;  // rt: o2/64 (32), ct: d/64 (8)
  const float* src = (s == 0) ? w21 : (s == 1) ? w22 : (s == 2) ? w23 : w24;
  const int tr = threadIdx.x >> 4;            // 0..15
  const int tc = (threadIdx.x & 15) << 2;     // 0..60
#pragma unroll
  for (int i = 0; i < 4; ++i) {
    const float4 v = *(const float4*)(src + (size_t)(rt * 64 + tr + 16 * i) * 512 + ct * 64 + tc);
    lds[tr + 16 * i][tc + 0] = v.x; lds[tr + 16 * i][tc + 1] = v.y;
    lds[tr + 16 * i][tc + 2] = v.z; lds[tr + 16 * i][tc + 3] = v.w;
  }
  __syncthreads();
#pragma unroll
  for (int i = 0; i < 4; ++i) {
    ushort4 ov;
    ov.x = f2bf(lds[tc + 0][tr + 16 * i]); ov.y = f2bf(lds[tc + 1][tr + 16 * i]);
    ov.z = f2bf(lds[tc + 2][tr + 16 * i]); ov.w = f2bf(lds[tc + 3][tr + 16 * i]);
    *(ushort4*)(w2t + ((size_t)s * 512 + ct * 64 + tr + 16 * i) * 2048 + rt * 64 + tc) = ov;
  }
}

__global__ __launch_bounds__(256) void prep_wen(const float* __restrict__ w_emb,
                                                const float* __restrict__ w_node,
                                                unsigned short* __restrict__ wen) {
  const int tid = blockIdx.x * 256 + threadIdx.x;   // 393,216
  const int r = tid >> 9;                           // 0..767
  const int k = (tid & 511) << 2;
  float4 vv = make_float4(0.f, 0.f, 0.f, 0.f);
  if (r < 300)       vv = *(const float4*)(w_emb + (size_t)r * 2048 + k);
  else if (r < 691)  vv = *(const float4*)(w_node + (size_t)(r - 300) * 2048 + k);
  ushort4 ov;
  ov.x = f2bf(vv.x); ov.y = f2bf(vv.y); ov.z = f2bf(vv.z); ov.w = f2bf(vv.w);
  *(ushort4*)(wen + (size_t)r * 2048 + k) = ov;
}

// ENb[s][e] = dot(WEN_row_e (f32 sources), b2_s)  — one wave per output
__global__ __launch_bounds__(256) void prep_enb(const float* __restrict__ wemb,
                                                const float* __restrict__ wnode,
                                                const float* b21, const float* b22,
                                                const float* b23, const float* b24,
                                                float* __restrict__ ENb) {
  const int w = blockIdx.x * 4 + (threadIdx.x >> 6);   // 0..3071
  const int lane = threadIdx.x & 63;
  const int s = w / 768, e = w % 768;
  const float* b2 = (s == 0) ? b21 : (s == 1) ? b22 : (s == 2) ? b23 : b24;
  float acc = 0.f;
  if (e < 691) {
    const float* row = (e < 300) ? (wemb + (size_t)e * 2048) : (wnode + (size_t)(e - 300) * 2048);
#pragma unroll
    for (int i = 0; i < 8; ++i) {
      const float4 a  = *(const float4*)(row + i * 256 + lane * 4);
      const float4 bb = *(const float4*)(b2  + i * 256 + lane * 4);
      acc += a.x * bb.x + a.y * bb.y + a.z * bb.z + a.w * bb.w;
    }
  }
#pragma unroll
  for (int off = 32; off; off >>= 1) acc += __shfl_down(acc, off);
  if (lane == 0) ENb[w] = acc;
}

// combine1: h1[c*512+b, o] = relu(b1_s[o] + sum_t H0p[P[c][t]*512 + b, o]) -> bf16
__global__ __launch_bounds__(128) void combine1_k(const unsigned short* __restrict__ H0p,
                                                  unsigned short* __restrict__ h1,
                                                  const float* __restrict__ b11,
                                                  const float* __restrict__ b12,
                                                  const float* __restrict__ b13,
                                                  const float* __restrict__ b14) {
  const int cb = blockIdx.x;            // 0..7679 = c*512+b
  const int c = cb >> 9, b = cb & 511;
  const int s = (c < 4) ? 1 : (c < 10) ? 2 : (c < 14) ? 3 : 4;
  const unsigned char P[15][4] = {
    {0,0,0,0},{1,0,0,0},{2,0,0,0},{3,0,0,0},
    {4,7,0,0},{4,8,0,0},{4,9,0,0},{5,8,0,0},{5,9,0,0},{6,9,0,0},
    {10,12,14,0},{10,12,15,0},{10,13,15,0},{11,13,15,0},
    {16,17,18,19}};
  const float* b1 = (s == 1) ? b11 : (s == 2) ? b12 : (s == 3) ? b13 : b14;
  const int o = threadIdx.x << 2;
  float4 a = *(const float4*)(b1 + o);
  for (int t = 0; t < s; ++t) {
    const int p = P[c][t];
    const ushort4 hv = *(const ushort4*)(H0p + ((size_t)(p * 512 + b)) * 512 + o);
    a.x += bf2f(hv.x); a.y += bf2f(hv.y); a.z += bf2f(hv.z); a.w += bf2f(hv.w);
  }
  ushort4 ov;
  ov.x = f2bf(fmaxf(a.x, 0.f)); ov.y = f2bf(fmaxf(a.y, 0.f));
  ov.z = f2bf(fmaxf(a.z, 0.f)); ov.w = f2bf(fmaxf(a.w, 0.f));
  *(ushort4*)(h1 + (size_t)cb * 512 + o) = ov;
}

// combine2 (round-5 proven): INCL-sum over subsets + write both outputs
__global__ __launch_bounds__(256) void combine2_k(const float* __restrict__ EN0,
                                                  const float* __restrict__ b_emb,
                                                  const float* __restrict__ b_node,
                                                  float* __restrict__ out0,
                                                  float* __restrict__ out1) {
  const int b   = blockIdx.x;
  const int col = blockIdx.y * 256 + threadIdx.x;
  if (col >= 691) return;
  float vals[15];
#pragma unroll
  for (int j = 0; j < 15; ++j)
    vals[j] = EN0[((size_t)(j * 512 + b)) * 768 + col];
  const int MSK[15] = {1,2,4,8,3,5,9,6,10,12,7,11,13,14,15};
  if (col < 300) {
    const float be = b_emb[col];
#pragma unroll
    for (int i = 0; i < 15; ++i) {
      float sum = be;
#pragma unroll
      for (int j = 0; j < 15; ++j)
        if ((MSK[j] & MSK[i]) == MSK[j]) sum += vals[j];
      out0[((size_t)b * 15 + i) * 300 + col] = sum;
    }
  } else {
    const int v = col - 300;
    const float bn = b_node[v];
#pragma unroll
    for (int i = 0; i < 15; ++i) {
      float sum = bn;
#pragma unroll
      for (int j = 0; j < 15; ++j)
        if ((MSK[j] & MSK[i]) == MSK[j]) sum += vals[j];
      out1[((size_t)b * 391 + v) * 15 + i] = sum;
    }
  }
}

// ---------------------------------------------------------------------------
extern "C" void kernel_launch(void* const* d_in, const int* in_sizes, int n_in,
                              void* d_out, int out_size, void* d_ws, size_t ws_size,
                              hipStream_t stream) {
  const float* x     = (const float*)d_in[0];
  const float* w11   = (const float*)d_in[1];
  const float* b11   = (const float*)d_in[2];
  const float* w21   = (const float*)d_in[3];
  const float* b21   = (const float*)d_in[4];
  const float* w12   = (const float*)d_in[5];
  const float* b12   = (const float*)d_in[6];
  const float* w22   = (const float*)d_in[7];
  const float* b22   = (const float*)d_in[8];
  const float* w13   = (const float*)d_in[9];
  const float* b13   = (const float*)d_in[10];
  const float* w23   = (const float*)d_in[11];
  const float* b23   = (const float*)d_in[12];
  const float* w14   = (const float*)d_in[13];
  const float* b14   = (const float*)d_in[14];
  const float* w24   = (const float*)d_in[15];
  const float* b24   = (const float*)d_in[16];
  const float* wemb  = (const float*)d_in[17];
  const float* bemb  = (const float*)d_in[18];
  const float* wnode = (const float*)d_in[19];
  const float* bnode = (const float*)d_in[20];

  char* ws = (char*)d_ws;
  // layout (bytes); EN0 aliases xrb+w1cat (dead after mega1). peak ~62.4 MB
  unsigned short* xrb   = (unsigned short*)(ws + 0);                 //  8,388,608
  unsigned short* w1cat = (unsigned short*)(ws + 8388608);           // 20,971,520 -> 29,360,128
  unsigned short* w2t   = (unsigned short*)(ws + 29360128);          //  8,388,608 -> 37,748,736
  unsigned short* wen   = (unsigned short*)(ws + 37748736);          //  3,145,728 -> 40,894,464
  unsigned short* H0p   = (unsigned short*)(ws + 40894464);          // 10,485,760 -> 51,380,224
  unsigned short* W2EN  = (unsigned short*)(ws + 51380224);          //  3,145,728 -> 54,525,952
  float*          ENb   = (float*)(ws + 54525952);                   //     12,288 -> 54,538,240
  unsigned short* h1bf  = (unsigned short*)(ws + 54538240);          //  7,864,320 -> 62,402,560
  float*          EN0   = (float*)(ws + 0);                          // 23,592,960 (aliases xrb/w1cat)

  float* out0 = (float*)d_out;            // embeddings (512,15,300)
  float* out1 = out0 + 2304000;           // node_out^T (512,391,15)

  prep_xr   <<<4096, 256, 0, stream>>>(x, xrb);
  prep_w1cat<<<10240, 256, 0, stream>>>(w11, w12, w13, w14, w1cat);
  prep_w2t  <<<dim3(8, 32, 4), 256, 0, stream>>>(w21, w22, w23, w24, w2t);
  prep_wen  <<<1536, 256, 0, stream>>>(wemb, wnode, wen);
  prep_enb  <<<768, 256, 0, stream>>>(wemb, wnode, b21, b22, b23, b24, ENb);

  mega1_k   <<<416, 256, 0, stream>>>(xrb, w1cat, wen, w2t, H0p, W2EN);
  combine1_k<<<7680, 128, 0, stream>>>(H0p, h1bf, b11, b12, b13, b14);
  gemmF_k   <<<dim3(6, 60), 256, 0, stream>>>(h1bf, W2EN, ENb, EN0);
  combine2_k<<<dim3(512, 3), 256, 0, stream>>>(EN0, bemb, bnode, out0, out1);
}